// Round 1
// baseline (663.967 us; speedup 1.0000x reference)
//
#include <hip/hip_runtime.h>
#include <float.h>
#include <math.h>

// Problem constants (from reference)
#define N_DB   200000
#define D_EMB  512
#define K      32

// Kernel-1 config
#define NBLK   256
#define TPB    512
#define WAVES  (TPB / 64)                    // 8 waves/block
#define RPB    ((N_DB + NBLK - 1) / NBLK)    // 782 rows per block
#define NCAND  (NBLK * K)                    // 8192 candidates

// ---------------------------------------------------------------------------
// Kernel 1: per-block distance computation + local top-32 selection.
// One wave computes one row's distance: lane reads float4 at [lane] and
// [lane+64] (2 coalesced 1 KiB wave transactions per row).
// ---------------------------------------------------------------------------
__global__ __launch_bounds__(TPB) void knn_dist_topk(
    const float* __restrict__ x,
    const float* __restrict__ X_emb,
    float* __restrict__ cand_d,
    int*   __restrict__ cand_i)
{
    __shared__ float xs[D_EMB];
    __shared__ float dists[RPB];
    __shared__ float redv[WAVES];
    __shared__ int   redi[WAVES];

    const int tid  = threadIdx.x;
    const int wid  = tid >> 6;
    const int lane = tid & 63;
    const int base = blockIdx.x * RPB;
    const int rows = min(RPB, N_DB - base);

    // Stage query vector in LDS
    for (int i = tid; i < D_EMB; i += TPB) xs[i] = x[i];
    __syncthreads();

    const float4* xq = (const float4*)xs;
    const float4 q0 = xq[lane];
    const float4 q1 = xq[lane + 64];

    // Distance phase: wave `wid` handles rows wid, wid+8, ...
    for (int r = wid; r < rows; r += WAVES) {
        const float4* p = (const float4*)(X_emb + (size_t)(base + r) * D_EMB);
        float4 a = p[lane];
        float4 b = p[lane + 64];
        float s = 0.f, d;
        d = a.x - q0.x; s = fmaf(d, d, s);
        d = a.y - q0.y; s = fmaf(d, d, s);
        d = a.z - q0.z; s = fmaf(d, d, s);
        d = a.w - q0.w; s = fmaf(d, d, s);
        d = b.x - q1.x; s = fmaf(d, d, s);
        d = b.y - q1.y; s = fmaf(d, d, s);
        d = b.z - q1.z; s = fmaf(d, d, s);
        d = b.w - q1.w; s = fmaf(d, d, s);
        #pragma unroll
        for (int off = 32; off > 0; off >>= 1) s += __shfl_xor(s, off);
        if (lane == 0) dists[r] = sqrtf(s);
    }
    __syncthreads();

    // Selection phase: 32 masked arg-min passes over LDS dists
    for (int it = 0; it < K; ++it) {
        float bv = FLT_MAX;
        int   bi = 0x7FFFFFFF;
        for (int i = tid; i < rows; i += TPB) {
            float v = dists[i];
            if (v < bv) { bv = v; bi = i; }   // strict < keeps lowest index
        }
        #pragma unroll
        for (int off = 32; off > 0; off >>= 1) {
            float ov = __shfl_xor(bv, off);
            int   oi = __shfl_xor(bi, off);
            if (ov < bv || (ov == bv && oi < bi)) { bv = ov; bi = oi; }
        }
        if (lane == 0) { redv[wid] = bv; redi[wid] = bi; }
        __syncthreads();
        if (tid == 0) {
            float v = redv[0]; int b = redi[0];
            #pragma unroll
            for (int w = 1; w < WAVES; ++w) {
                if (redv[w] < v || (redv[w] == v && redi[w] < b)) {
                    v = redv[w]; b = redi[w];
                }
            }
            cand_d[blockIdx.x * K + it] = v;
            cand_i[blockIdx.x * K + it] = base + b;
            if (b >= 0 && b < rows) dists[b] = FLT_MAX;  // mask selected
        }
        __syncthreads();
    }
}

// ---------------------------------------------------------------------------
// Kernel 2: reduce 8192 candidates -> global top-32 (ascending), gather
// neighbor rows / classes / distances into d_out.
// Candidate slot order equals db-index order for equal distances (blocks are
// contiguous chunks; within-block ranks tie-break by lowest index), so
// slot-order tie-break reproduces jax.lax.top_k's lowest-index semantics.
// ---------------------------------------------------------------------------
__global__ __launch_bounds__(256) void knn_final(
    const float* __restrict__ X_emb,
    const int*   __restrict__ X_cls,
    const float* __restrict__ cand_d,
    const int*   __restrict__ cand_i,
    float* __restrict__ out)
{
    __shared__ float cd[NCAND];      // 32 KiB
    __shared__ float redv[4];
    __shared__ int   redi[4];
    __shared__ int   sel_i[K];
    __shared__ float sel_d[K];

    const int tid  = threadIdx.x;
    const int wid  = tid >> 6;
    const int lane = tid & 63;

    for (int i = tid; i < NCAND; i += 256) cd[i] = cand_d[i];
    __syncthreads();

    for (int it = 0; it < K; ++it) {
        float bv = FLT_MAX;
        int   bi = 0x7FFFFFFF;
        for (int i = tid; i < NCAND; i += 256) {
            float v = cd[i];
            if (v < bv) { bv = v; bi = i; }
        }
        #pragma unroll
        for (int off = 32; off > 0; off >>= 1) {
            float ov = __shfl_xor(bv, off);
            int   oi = __shfl_xor(bi, off);
            if (ov < bv || (ov == bv && oi < bi)) { bv = ov; bi = oi; }
        }
        if (lane == 0) { redv[wid] = bv; redi[wid] = bi; }
        __syncthreads();
        if (tid == 0) {
            float v = redv[0]; int b = redi[0];
            #pragma unroll
            for (int w = 1; w < 4; ++w) {
                if (redv[w] < v || (redv[w] == v && redi[w] < b)) {
                    v = redv[w]; b = redi[w];
                }
            }
            sel_d[it] = v;
            sel_i[it] = cand_i[b];   // one L2 read by thread 0
            cd[b] = FLT_MAX;
        }
        __syncthreads();
    }

    // Gather: out layout = emb[32*512] | cls[32] | dist[32]
    float4* out_emb = (float4*)out;
    for (int r = wid; r < K; r += 4) {
        const float4* p = (const float4*)(X_emb + (size_t)sel_i[r] * D_EMB);
        out_emb[r * 128 + lane]      = p[lane];
        out_emb[r * 128 + lane + 64] = p[lane + 64];
    }
    if (tid < K) {
        out[K * D_EMB + tid]     = (float)X_cls[sel_i[tid]];
        out[K * D_EMB + K + tid] = sel_d[tid];
    }
}

extern "C" void kernel_launch(void* const* d_in, const int* in_sizes, int n_in,
                              void* d_out, int out_size, void* d_ws, size_t ws_size,
                              hipStream_t stream) {
    const float* x     = (const float*)d_in[0];
    const float* X_emb = (const float*)d_in[1];
    const int*   X_cls = (const int*)d_in[2];
    // d_in[3] is k == 32 (hard-coded)

    float* cand_d = (float*)d_ws;
    int*   cand_i = (int*)((char*)d_ws + NCAND * sizeof(float));

    knn_dist_topk<<<NBLK, TPB, 0, stream>>>(x, X_emb, cand_d, cand_i);
    knn_final<<<1, 256, 0, stream>>>(X_emb, X_cls, cand_d, cand_i, (float*)d_out);
}